// Round 1
// baseline (1550.049 us; speedup 1.0000x reference)
//
#include <hip/hip_runtime.h>
#include <math.h>

#define NH 5
#define NC 64
#define ED 16
#define HC 320   // NH*NC

// ---------------- preprocessing ----------------

// count in-degree (real edges) + accumulate edge_attr sums per dst
__global__ void count_kernel(const int* __restrict__ dst, const float* __restrict__ ea,
                             float* __restrict__ loop_sum, int* __restrict__ cnt, int E) {
    int t = blockIdx.x * blockDim.x + threadIdx.x;
    if (t >= E * ED) return;
    int e = t >> 4, k = t & 15;
    int d = dst[e];
    atomicAdd(&loop_sum[(size_t)d * ED + k], ea[t]);
    if (k == 0) atomicAdd(&cnt[d], 1);
}

// loop_attr = loop_sum / max(cnt,1)  (in place)
__global__ void finalize_loop(float* __restrict__ loop_sum, const int* __restrict__ cnt, int N) {
    int t = blockIdx.x * blockDim.x + threadIdx.x;
    if (t >= N * ED) return;
    int n = t >> 4;
    float c = (float)max(cnt[n], 1);
    loop_sum[t] = loop_sum[t] / c;
}

// single-block exclusive scan of (cnt[i]+1) -> offsets, cursor; offsets[N] = total
__global__ void scan_kernel(const int* __restrict__ cnt, int* __restrict__ offsets,
                            int* __restrict__ cursor, int N) {
    __shared__ int sums[1024];
    int t = threadIdx.x;
    int chunk = (N + 1023) / 1024;
    int beg = t * chunk;
    int end = min(beg + chunk, N);
    int s = 0;
    for (int i = beg; i < end; ++i) s += cnt[i] + 1;
    sums[t] = s;
    __syncthreads();
    for (int o = 1; o < 1024; o <<= 1) {
        int v = (t >= o) ? sums[t - o] : 0;
        __syncthreads();
        sums[t] += v;
        __syncthreads();
    }
    int run = (t > 0) ? sums[t - 1] : 0;
    for (int i = beg; i < end; ++i) {
        offsets[i] = run; cursor[i] = run;
        run += cnt[i] + 1;
    }
    if (t == 0) offsets[N] = sums[1023];
}

// scatter edge ids into CSR slots (order within a node is irrelevant)
__global__ void scatter_kernel(const int* __restrict__ dst, int* __restrict__ cursor,
                               int* __restrict__ eid, int N, int E) {
    int t = blockIdx.x * blockDim.x + threadIdx.x;
    if (t >= E + N) return;
    int d = (t < E) ? dst[t] : (t - E);
    int pos = atomicAdd(&cursor[d], 1);
    eid[pos] = t;
}

// ---------------- GEMM: C[M,320] = A[M,K] @ B[K,320] + bias ----------------
__global__ __launch_bounds__(256) void gemm_bias(const float* __restrict__ A,
                                                 const float* __restrict__ B,
                                                 const float* __restrict__ bias,
                                                 float* __restrict__ Cout, int M, int K) {
    __shared__ float As[64][17];
    __shared__ float Bs[16][64];
    int tid = threadIdx.x;
    int tx = tid & 15, ty = tid >> 4;
    int rowBase = blockIdx.y * 64;
    int colBase = blockIdx.x * 64;
    int lr = tid >> 2;          // A-load row within tile
    int lk = (tid & 3) * 4;     // A-load k offset
    int bkk = tid >> 4;         // B-load k within tile
    int bc = (tid & 15) * 4;    // B-load col within tile
    float acc[4][4] = {};
    for (int k0 = 0; k0 < K; k0 += 16) {
        float4 av = make_float4(0.f, 0.f, 0.f, 0.f);
        int gr = rowBase + lr;
        if (gr < M) av = *(const float4*)&A[(size_t)gr * K + k0 + lk];
        As[lr][lk + 0] = av.x; As[lr][lk + 1] = av.y;
        As[lr][lk + 2] = av.z; As[lr][lk + 3] = av.w;
        float4 bv = *(const float4*)&B[(size_t)(k0 + bkk) * HC + colBase + bc];
        *(float4*)&Bs[bkk][bc] = bv;
        __syncthreads();
#pragma unroll
        for (int kk = 0; kk < 16; ++kk) {
            float4 b = *(float4*)&Bs[kk][tx * 4];
            float a0 = As[ty * 4 + 0][kk];
            float a1 = As[ty * 4 + 1][kk];
            float a2 = As[ty * 4 + 2][kk];
            float a3 = As[ty * 4 + 3][kk];
            acc[0][0] = fmaf(a0, b.x, acc[0][0]); acc[0][1] = fmaf(a0, b.y, acc[0][1]);
            acc[0][2] = fmaf(a0, b.z, acc[0][2]); acc[0][3] = fmaf(a0, b.w, acc[0][3]);
            acc[1][0] = fmaf(a1, b.x, acc[1][0]); acc[1][1] = fmaf(a1, b.y, acc[1][1]);
            acc[1][2] = fmaf(a1, b.z, acc[1][2]); acc[1][3] = fmaf(a1, b.w, acc[1][3]);
            acc[2][0] = fmaf(a2, b.x, acc[2][0]); acc[2][1] = fmaf(a2, b.y, acc[2][1]);
            acc[2][2] = fmaf(a2, b.z, acc[2][2]); acc[2][3] = fmaf(a2, b.w, acc[2][3]);
            acc[3][0] = fmaf(a3, b.x, acc[3][0]); acc[3][1] = fmaf(a3, b.y, acc[3][1]);
            acc[3][2] = fmaf(a3, b.z, acc[3][2]); acc[3][3] = fmaf(a3, b.w, acc[3][3]);
        }
        __syncthreads();
    }
    int col = colBase + tx * 4;
    float4 bb = *(const float4*)&bias[col];
#pragma unroll
    for (int i = 0; i < 4; ++i) {
        int r = rowBase + ty * 4 + i;
        if (r < M) {
            float4 v = make_float4(acc[i][0] + bb.x, acc[i][1] + bb.y,
                                   acc[i][2] + bb.z, acc[i][3] + bb.w);
            *(float4*)&Cout[(size_t)r * HC + col] = v;
        }
    }
}

// ---------------- fused edge logits + softmax + aggregation (one wave per dst node) ----------------
__global__ __launch_bounds__(256) void gat_edge(const float* __restrict__ hbuf,   // [N,320]
                                                const int* __restrict__ offsets,  // [N+1]
                                                const int* __restrict__ eid,      // [E+N]
                                                const int* __restrict__ srcArr,   // [E]
                                                const float* __restrict__ ea,     // [E,16]
                                                const float* __restrict__ loopAttr,// [N,16]
                                                const float* __restrict__ We,     // [16,320]
                                                const float* __restrict__ att,    // [5,64]
                                                const float* __restrict__ bias,   // [64]
                                                float* __restrict__ out,          // [N,64]
                                                int N, int E) {
    int lane = threadIdx.x & 63;
    int wave = (blockIdx.x * blockDim.x + threadIdx.x) >> 6;
    int nw = (gridDim.x * blockDim.x) >> 6;
    int c = lane;

    float we[ED * NH];
#pragma unroll
    for (int k = 0; k < ED; ++k)
#pragma unroll
        for (int h = 0; h < NH; ++h)
            we[k * NH + h] = We[k * HC + h * NC + c];
    float attc[NH];
#pragma unroll
    for (int h = 0; h < NH; ++h) attc[h] = att[h * NC + c];
    float bc = bias[c];

    for (int i = wave; i < N; i += nw) {
        int beg = offsets[i], end = offsets[i + 1];
        float hd[NH];
#pragma unroll
        for (int h = 0; h < NH; ++h) hd[h] = hbuf[(size_t)i * HC + h * NC + c];
        float m[NH], l[NH], acc[NH];
#pragma unroll
        for (int h = 0; h < NH; ++h) { m[h] = -INFINITY; l[h] = 0.f; acc[h] = 0.f; }

        for (int t = beg; t < end; ++t) {
            int e = eid[t];
            int s; const float* ap;
            if (e < E) { s = srcArr[e]; ap = ea + (size_t)e * ED; }
            else       { s = e - E;    ap = loopAttr + (size_t)s * ED; }
            float a[ED];
#pragma unroll
            for (int k = 0; k < ED; ++k) a[k] = ap[k];   // wave-uniform → 1 cache line
            float hs[NH];
#pragma unroll
            for (int h = 0; h < NH; ++h) hs[h] = hbuf[(size_t)s * HC + h * NC + c];
#pragma unroll
            for (int h = 0; h < NH; ++h) {
                float v = hd[h] + hs[h];
#pragma unroll
                for (int k = 0; k < ED; ++k) v = fmaf(a[k], we[k * NH + h], v);
                v = v > 0.f ? v : 0.2f * v;          // leaky_relu
                float p = v * attc[h];
#pragma unroll
                for (int off = 32; off > 0; off >>= 1) p += __shfl_xor(p, off, 64);
                // p == logit[h], identical on all lanes; online softmax update
                float mn = fmaxf(m[h], p);
                float sc = __expf(m[h] - mn);        // exp(-inf)=0 on first edge
                float pe = __expf(p - mn);
                l[h] = l[h] * sc + pe;
                acc[h] = acc[h] * sc + pe * hs[h];
                m[h] = mn;
            }
        }
        float o = 0.f;
#pragma unroll
        for (int h = 0; h < NH; ++h) o += acc[h] / l[h];
        o = o * 0.2f + bc;                            // head mean + bias
        o = o > 0.f ? o : expm1f(o);                  // ELU
        out[(size_t)i * NC + c] = o;
    }
}

// ---------------- launch ----------------
extern "C" void kernel_launch(void* const* d_in, const int* in_sizes, int n_in,
                              void* d_out, int out_size, void* d_ws, size_t ws_size,
                              hipStream_t stream) {
    const float* x     = (const float*)d_in[0];
    const int*   ei    = (const int*)d_in[1];
    const float* ea    = (const float*)d_in[2];
    const float* W0    = (const float*)d_in[3];
    const float* b0    = (const float*)d_in[4];
    const float* We0   = (const float*)d_in[5];
    const float* att0  = (const float*)d_in[6];
    const float* bias0 = (const float*)d_in[7];
    const float* W12   = (const float*)d_in[8];
    const float* b12   = (const float*)d_in[9];
    const float* We12  = (const float*)d_in[10];
    const float* att12 = (const float*)d_in[11];
    const float* bias12= (const float*)d_in[12];

    int N = in_sizes[0] / 128;
    int E = in_sizes[1] / 2;
    const int* srcArr = ei;
    const int* dstArr = ei + E;

    char* ws = (char*)d_ws;
    size_t off = 0;
    auto alloc = [&](size_t bytes) -> void* {
        void* p = ws + off;
        off = (off + bytes + 255) & ~(size_t)255;
        return p;
    };
    int*   cnt     = (int*)alloc((size_t)N * 4);
    int*   offsets = (int*)alloc((size_t)(N + 1) * 4);
    int*   cursor  = (int*)alloc((size_t)N * 4);
    int*   eidb    = (int*)alloc((size_t)(E + N) * 4);
    float* loop    = (float*)alloc((size_t)N * ED * 4);
    float* hbuf    = (float*)alloc((size_t)N * HC * 4);
    float* act     = (float*)alloc((size_t)N * NC * 4);

    hipMemsetAsync(cnt, 0, (size_t)N * 4, stream);
    hipMemsetAsync(loop, 0, (size_t)N * ED * 4, stream);
    count_kernel<<<(E * ED + 255) / 256, 256, 0, stream>>>(dstArr, ea, loop, cnt, E);
    finalize_loop<<<(N * ED + 255) / 256, 256, 0, stream>>>(loop, cnt, N);
    scan_kernel<<<1, 1024, 0, stream>>>(cnt, offsets, cursor, N);
    scatter_kernel<<<(E + N + 255) / 256, 256, 0, stream>>>(dstArr, cursor, eidb, N, E);

    float* dout = (float*)d_out;
    dim3 gg(HC / 64, (N + 63) / 64);

    // layer 0
    gemm_bias<<<gg, 256, 0, stream>>>(x, W0, b0, hbuf, N, 128);
    gat_edge<<<1024, 256, 0, stream>>>(hbuf, offsets, eidb, srcArr, ea, loop,
                                       We0, att0, bias0, act, N, E);
    // layer 1
    gemm_bias<<<gg, 256, 0, stream>>>(act, W12, b12, hbuf, N, 64);
    gat_edge<<<1024, 256, 0, stream>>>(hbuf, offsets, eidb, srcArr, ea, loop,
                                       We12, att12, bias12, act, N, E);
    // layer 2
    gemm_bias<<<gg, 256, 0, stream>>>(act, W12 + 64 * HC, b12 + HC, hbuf, N, 64);
    gat_edge<<<1024, 256, 0, stream>>>(hbuf, offsets, eidb, srcArr, ea, loop,
                                       We12 + ED * HC, att12 + NH * NC, bias12 + NC, dout, N, E);
}

// Round 2
// 1163.463 us; speedup vs baseline: 1.3323x; 1.3323x over previous
//
#include <hip/hip_runtime.h>
#include <hip/hip_fp16.h>
#include <math.h>

#define NH 5
#define NC 64
#define ED 16
#define HC 320   // NH*NC

// ---------------- preprocessing ----------------

// in-degree count (real edges only)
__global__ void count_kernel(const int* __restrict__ dst, int* __restrict__ cnt, int E) {
    int t = blockIdx.x * blockDim.x + threadIdx.x;
    if (t >= E) return;
    atomicAdd(&cnt[dst[t]], 1);
}

// single-block exclusive scan of (cnt[i]+1) -> offsets, cursor; offsets[N] = total
__global__ void scan_kernel(const int* __restrict__ cnt, int* __restrict__ offsets,
                            int* __restrict__ cursor, int N) {
    __shared__ int sums[1024];
    int t = threadIdx.x;
    int chunk = (N + 1023) / 1024;
    int beg = t * chunk;
    int end = min(beg + chunk, N);
    int s = 0;
    for (int i = beg; i < end; ++i) s += cnt[i] + 1;
    sums[t] = s;
    __syncthreads();
    for (int o = 1; o < 1024; o <<= 1) {
        int v = (t >= o) ? sums[t - o] : 0;
        __syncthreads();
        sums[t] += v;
        __syncthreads();
    }
    int run = (t > 0) ? sums[t - 1] : 0;
    for (int i = beg; i < end; ++i) {
        offsets[i] = run; cursor[i] = run;
        run += cnt[i] + 1;
    }
    if (t == 0) offsets[N] = sums[1023];
}

// scatter {src, attr_row} records into CSR slots
__global__ void scatter_kernel(const int* __restrict__ src, const int* __restrict__ dst,
                               int* __restrict__ cursor, int2* __restrict__ recs, int N, int E) {
    int t = blockIdx.x * blockDim.x + threadIdx.x;
    if (t >= E + N) return;
    int d, s;
    if (t < E) { d = dst[t]; s = src[t]; }
    else       { d = t - E; s = t - E; }
    int pos = atomicAdd(&cursor[d], 1);
    recs[pos] = make_int2(s, t);   // attr row t: <E -> ea row, >=E -> loop row (t-E)
}

// self-loop attr = mean of incoming real-edge attrs, computed from CSR (no float atomics)
__global__ void loop_from_csr(const int* __restrict__ offsets, const int2* __restrict__ recs,
                              const float* __restrict__ ea, float* __restrict__ loop,
                              int N, int E) {
    int t = blockIdx.x * blockDim.x + threadIdx.x;
    int n = t >> 4, k = t & 15;
    if (n >= N) return;
    int beg = offsets[n], end = offsets[n + 1];
    float s = 0.f; int c = 0;
    for (int j = beg; j < end; ++j) {
        int y = recs[j].y;
        if (y < E) { s += ea[(size_t)y * ED + k]; ++c; }
    }
    loop[(size_t)n * ED + k] = s / (float)max(c, 1);
}

// ---------------- ew = attr @ We  (fp16 out), rows 0..E-1 from ea, E..E+N-1 from loop
__global__ __launch_bounds__(256) void ew_gemm(const float* __restrict__ ea,
                                               const float* __restrict__ loop,
                                               const float* __restrict__ We,
                                               __half* __restrict__ ew, int R, int E) {
    int lane = threadIdx.x & 63;
    int wave = (blockIdx.x * blockDim.x + threadIdx.x) >> 6;
    int nw = (gridDim.x * blockDim.x) >> 6;
    float we[ED * NH];
#pragma unroll
    for (int k = 0; k < ED; ++k)
#pragma unroll
        for (int h = 0; h < NH; ++h)
            we[k * NH + h] = We[k * HC + h * NC + lane];
    for (int r = wave; r < R; r += nw) {
        const float* ap = (r < E) ? ea + (size_t)r * ED : loop + (size_t)(r - E) * ED;
        float a[ED];
#pragma unroll
        for (int k = 0; k < ED; ++k) a[k] = ap[k];
        __half* op = ew + (size_t)r * HC;
#pragma unroll
        for (int h = 0; h < NH; ++h) {
            float v = 0.f;
#pragma unroll
            for (int k = 0; k < ED; ++k) v = fmaf(a[k], we[k * NH + h], v);
            op[h * NC + lane] = __float2half(v);
        }
    }
}

// ---------------- GEMM: C[M,320] = A[M,K] @ B[K,320] + bias ----------------
__global__ __launch_bounds__(256) void gemm_bias(const float* __restrict__ A,
                                                 const float* __restrict__ B,
                                                 const float* __restrict__ bias,
                                                 float* __restrict__ Cout, int M, int K) {
    __shared__ float As[64][17];
    __shared__ float Bs[16][64];
    int tid = threadIdx.x;
    int tx = tid & 15, ty = tid >> 4;
    int rowBase = blockIdx.y * 64;
    int colBase = blockIdx.x * 64;
    int lr = tid >> 2;
    int lk = (tid & 3) * 4;
    int bkk = tid >> 4;
    int bc = (tid & 15) * 4;
    float acc[4][4] = {};
    for (int k0 = 0; k0 < K; k0 += 16) {
        float4 av = make_float4(0.f, 0.f, 0.f, 0.f);
        int gr = rowBase + lr;
        if (gr < M) av = *(const float4*)&A[(size_t)gr * K + k0 + lk];
        As[lr][lk + 0] = av.x; As[lr][lk + 1] = av.y;
        As[lr][lk + 2] = av.z; As[lr][lk + 3] = av.w;
        float4 bv = *(const float4*)&B[(size_t)(k0 + bkk) * HC + colBase + bc];
        *(float4*)&Bs[bkk][bc] = bv;
        __syncthreads();
#pragma unroll
        for (int kk = 0; kk < 16; ++kk) {
            float4 b = *(float4*)&Bs[kk][tx * 4];
            float a0 = As[ty * 4 + 0][kk];
            float a1 = As[ty * 4 + 1][kk];
            float a2 = As[ty * 4 + 2][kk];
            float a3 = As[ty * 4 + 3][kk];
            acc[0][0] = fmaf(a0, b.x, acc[0][0]); acc[0][1] = fmaf(a0, b.y, acc[0][1]);
            acc[0][2] = fmaf(a0, b.z, acc[0][2]); acc[0][3] = fmaf(a0, b.w, acc[0][3]);
            acc[1][0] = fmaf(a1, b.x, acc[1][0]); acc[1][1] = fmaf(a1, b.y, acc[1][1]);
            acc[1][2] = fmaf(a1, b.z, acc[1][2]); acc[1][3] = fmaf(a1, b.w, acc[1][3]);
            acc[2][0] = fmaf(a2, b.x, acc[2][0]); acc[2][1] = fmaf(a2, b.y, acc[2][1]);
            acc[2][2] = fmaf(a2, b.z, acc[2][2]); acc[2][3] = fmaf(a2, b.w, acc[2][3]);
            acc[3][0] = fmaf(a3, b.x, acc[3][0]); acc[3][1] = fmaf(a3, b.y, acc[3][1]);
            acc[3][2] = fmaf(a3, b.z, acc[3][2]); acc[3][3] = fmaf(a3, b.w, acc[3][3]);
        }
        __syncthreads();
    }
    int col = colBase + tx * 4;
    float4 bb = *(const float4*)&bias[col];
#pragma unroll
    for (int i = 0; i < 4; ++i) {
        int r = rowBase + ty * 4 + i;
        if (r < M) {
            float4 v = make_float4(acc[i][0] + bb.x, acc[i][1] + bb.y,
                                   acc[i][2] + bb.z, acc[i][3] + bb.w);
            *(float4*)&Cout[(size_t)r * HC + col] = v;
        }
    }
}

// ---------------- fused softmax+aggregate, ew precomputed (one wave per dst node) ---------
__device__ __forceinline__ void gat_step(const float* hs, const float* e, const float* hd,
                                         const float* attc, float* m, float* l, float* acc) {
#pragma unroll
    for (int h = 0; h < NH; ++h) {
        float v = hd[h] + hs[h] + e[h];
        v = v > 0.f ? v : 0.2f * v;
        float p = v * attc[h];
#pragma unroll
        for (int off = 32; off > 0; off >>= 1) p += __shfl_xor(p, off, 64);
        float mn = fmaxf(m[h], p);
        float sc = __expf(m[h] - mn);
        float pe = __expf(p - mn);
        l[h] = l[h] * sc + pe;
        acc[h] = acc[h] * sc + pe * hs[h];
        m[h] = mn;
    }
}

__global__ __launch_bounds__(256) void gat_edge_ew(const float* __restrict__ hbuf,
                                                   const int* __restrict__ offsets,
                                                   const int2* __restrict__ recs,
                                                   const __half* __restrict__ ew,
                                                   const float* __restrict__ att,
                                                   const float* __restrict__ bias,
                                                   float* __restrict__ out, int N) {
    int lane = threadIdx.x & 63;
    int wave = (blockIdx.x * blockDim.x + threadIdx.x) >> 6;
    int nw = (gridDim.x * blockDim.x) >> 6;
    float attc[NH];
#pragma unroll
    for (int h = 0; h < NH; ++h) attc[h] = att[h * NC + lane];
    float bc = bias[lane];

    for (int i = wave; i < N; i += nw) {
        int beg = offsets[i], end = offsets[i + 1];
        float hd[NH];
#pragma unroll
        for (int h = 0; h < NH; ++h) hd[h] = hbuf[(size_t)i * HC + h * NC + lane];
        float m[NH], l[NH], acc[NH];
#pragma unroll
        for (int h = 0; h < NH; ++h) { m[h] = -INFINITY; l[h] = 0.f; acc[h] = 0.f; }

        // double-buffered edge pipeline
        float e0[NH], hs0[NH], e1[NH], hs1[NH];
        {
            int2 r = recs[beg];
            const __half* ep = ew + (size_t)r.y * HC;
            const float* hp = hbuf + (size_t)r.x * HC;
#pragma unroll
            for (int h = 0; h < NH; ++h) { e0[h] = __half2float(ep[h * NC + lane]); hs0[h] = hp[h * NC + lane]; }
        }
        int t = beg;
        while (true) {
            if (t + 1 < end) {
                int2 r = recs[t + 1];
                const __half* ep = ew + (size_t)r.y * HC;
                const float* hp = hbuf + (size_t)r.x * HC;
#pragma unroll
                for (int h = 0; h < NH; ++h) { e1[h] = __half2float(ep[h * NC + lane]); hs1[h] = hp[h * NC + lane]; }
            }
            gat_step(hs0, e0, hd, attc, m, l, acc);
            ++t; if (t >= end) break;
            if (t + 1 < end) {
                int2 r = recs[t + 1];
                const __half* ep = ew + (size_t)r.y * HC;
                const float* hp = hbuf + (size_t)r.x * HC;
#pragma unroll
                for (int h = 0; h < NH; ++h) { e0[h] = __half2float(ep[h * NC + lane]); hs0[h] = hp[h * NC + lane]; }
            }
            gat_step(hs1, e1, hd, attc, m, l, acc);
            ++t; if (t >= end) break;
        }
        float o = 0.f;
#pragma unroll
        for (int h = 0; h < NH; ++h) o += acc[h] / l[h];
        o = o * 0.2f + bc;
        o = o > 0.f ? o : expm1f(o);
        out[(size_t)i * NC + lane] = o;
    }
}

// ---------------- fallback: recompute ea@We in-kernel (no ew workspace) ----------------
__global__ __launch_bounds__(256) void gat_edge_fb(const float* __restrict__ hbuf,
                                                   const int* __restrict__ offsets,
                                                   const int2* __restrict__ recs,
                                                   const float* __restrict__ ea,
                                                   const float* __restrict__ loopAttr,
                                                   const float* __restrict__ We,
                                                   const float* __restrict__ att,
                                                   const float* __restrict__ bias,
                                                   float* __restrict__ out, int N, int E) {
    int lane = threadIdx.x & 63;
    int wave = (blockIdx.x * blockDim.x + threadIdx.x) >> 6;
    int nw = (gridDim.x * blockDim.x) >> 6;
    float we[ED * NH];
#pragma unroll
    for (int k = 0; k < ED; ++k)
#pragma unroll
        for (int h = 0; h < NH; ++h)
            we[k * NH + h] = We[k * HC + h * NC + lane];
    float attc[NH];
#pragma unroll
    for (int h = 0; h < NH; ++h) attc[h] = att[h * NC + lane];
    float bc = bias[lane];

    for (int i = wave; i < N; i += nw) {
        int beg = offsets[i], end = offsets[i + 1];
        float hd[NH];
#pragma unroll
        for (int h = 0; h < NH; ++h) hd[h] = hbuf[(size_t)i * HC + h * NC + lane];
        float m[NH], l[NH], acc[NH];
#pragma unroll
        for (int h = 0; h < NH; ++h) { m[h] = -INFINITY; l[h] = 0.f; acc[h] = 0.f; }
        for (int t = beg; t < end; ++t) {
            int2 r = recs[t];
            const float* ap = (r.y < E) ? ea + (size_t)r.y * ED : loopAttr + (size_t)(r.y - E) * ED;
            float a[ED];
#pragma unroll
            for (int k = 0; k < ED; ++k) a[k] = ap[k];
            float hs[NH], e[NH];
#pragma unroll
            for (int h = 0; h < NH; ++h) {
                hs[h] = hbuf[(size_t)r.x * HC + h * NC + lane];
                float v = 0.f;
#pragma unroll
                for (int k = 0; k < ED; ++k) v = fmaf(a[k], we[k * NH + h], v);
                e[h] = v;
            }
            gat_step(hs, e, hd, attc, m, l, acc);
        }
        float o = 0.f;
#pragma unroll
        for (int h = 0; h < NH; ++h) o += acc[h] / l[h];
        o = o * 0.2f + bc;
        o = o > 0.f ? o : expm1f(o);
        out[(size_t)i * NC + lane] = o;
    }
}

// ---------------- launch ----------------
extern "C" void kernel_launch(void* const* d_in, const int* in_sizes, int n_in,
                              void* d_out, int out_size, void* d_ws, size_t ws_size,
                              hipStream_t stream) {
    const float* x     = (const float*)d_in[0];
    const int*   ei    = (const int*)d_in[1];
    const float* ea    = (const float*)d_in[2];
    const float* W0    = (const float*)d_in[3];
    const float* b0    = (const float*)d_in[4];
    const float* We0   = (const float*)d_in[5];
    const float* att0  = (const float*)d_in[6];
    const float* bias0 = (const float*)d_in[7];
    const float* W12   = (const float*)d_in[8];
    const float* b12   = (const float*)d_in[9];
    const float* We12  = (const float*)d_in[10];
    const float* att12 = (const float*)d_in[11];
    const float* bias12= (const float*)d_in[12];

    int N = in_sizes[0] / 128;
    int E = in_sizes[1] / 2;
    int R = E + N;
    const int* srcArr = ei;
    const int* dstArr = ei + E;

    char* ws = (char*)d_ws;
    size_t off = 0;
    auto alloc = [&](size_t bytes) -> void* {
        void* p = ws + off;
        off = (off + bytes + 255) & ~(size_t)255;
        return p;
    };
    int*   cnt     = (int*)alloc((size_t)N * 4);
    int*   offsets = (int*)alloc((size_t)(N + 1) * 4);
    int*   cursor  = (int*)alloc((size_t)N * 4);
    int2*  recs    = (int2*)alloc((size_t)(R + 1) * 8);
    float* loop    = (float*)alloc((size_t)N * ED * 4);
    float* hbuf    = (float*)alloc((size_t)N * HC * 4);
    float* act     = (float*)alloc((size_t)N * NC * 4);
    size_t base = off;
    __half* ew = (__half*)alloc((size_t)R * HC * 2);
    bool useEW = (ws_size >= base + (size_t)R * HC * 2 + 256);

    hipMemsetAsync(cnt, 0, (size_t)N * 4, stream);
    count_kernel<<<(E + 255) / 256, 256, 0, stream>>>(dstArr, cnt, E);
    scan_kernel<<<1, 1024, 0, stream>>>(cnt, offsets, cursor, N);
    scatter_kernel<<<(E + N + 255) / 256, 256, 0, stream>>>(srcArr, dstArr, cursor, recs, N, E);
    loop_from_csr<<<((size_t)N * ED + 255) / 256, 256, 0, stream>>>(offsets, recs, ea, loop, N, E);

    float* dout = (float*)d_out;
    dim3 gg(HC / 64, (N + 63) / 64);
    int edgeBlocks = (N + 3) / 4;   // one wave per node

    const float* Ws[3]   = {W0, W12, W12 + 64 * HC};
    const float* bs[3]   = {b0, b12, b12 + HC};
    const float* Wes[3]  = {We0, We12, We12 + ED * HC};
    const float* atts[3] = {att0, att12, att12 + NH * NC};
    const float* bis[3]  = {bias0, bias12, bias12 + NC};
    const float* in = x;
    int K = 128;
    for (int layer = 0; layer < 3; ++layer) {
        float* outp = (layer == 2) ? dout : act;
        gemm_bias<<<gg, 256, 0, stream>>>(in, Ws[layer], bs[layer], hbuf, N, K);
        if (useEW) {
            ew_gemm<<<2048, 256, 0, stream>>>(ea, loop, Wes[layer], ew, R, E);
            gat_edge_ew<<<edgeBlocks, 256, 0, stream>>>(hbuf, offsets, recs, ew,
                                                        atts[layer], bis[layer], outp, N);
        } else {
            gat_edge_fb<<<2048, 256, 0, stream>>>(hbuf, offsets, recs, ea, loop, Wes[layer],
                                                  atts[layer], bis[layer], outp, N, E);
        }
        in = act; K = 64;
    }
}